// Round 3
// baseline (500.938 us; speedup 1.0000x reference)
//
#include <hip/hip_runtime.h>

#define B_Q    1024
#define D_K    512
#define N_CLS  200
#define N_KEYS 50000
#define N_PAD  50048   // 391 * 128

typedef __attribute__((ext_vector_type(8))) short bf16x8;
typedef __attribute__((ext_vector_type(4))) float f32x4;

__device__ __forceinline__ float bf2f(unsigned short u) {
  union { unsigned int i; float f; } v; v.i = ((unsigned int)u) << 16; return v.f;
}
__device__ __forceinline__ unsigned short f2bf(float f) {
  union { float f; unsigned int i; } v; v.f = f;
  unsigned int r = v.i + 0x7fffu + ((v.i >> 16) & 1u);
  return (unsigned short)(r >> 16);
}
__device__ __forceinline__ uint4 pack8(const float f[8], float s) {
  uint4 o;
  o.x = (unsigned)f2bf(f[0]*s) | ((unsigned)f2bf(f[1]*s) << 16);
  o.y = (unsigned)f2bf(f[2]*s) | ((unsigned)f2bf(f[3]*s) << 16);
  o.z = (unsigned)f2bf(f[4]*s) | ((unsigned)f2bf(f[5]*s) << 16);
  o.w = (unsigned)f2bf(f[6]*s) | ((unsigned)f2bf(f[7]*s) << 16);
  return o;
}

// ---------------- label sort (counting sort) ----------------
__global__ void k_hist(const int* __restrict__ labels, int* __restrict__ hist) {
  __shared__ int h[N_CLS];
  int t = threadIdx.x;
  if (t < N_CLS) h[t] = 0;
  __syncthreads();
  int n = blockIdx.x * 256 + t;
  if (n < N_KEYS) atomicAdd(&h[labels[n]], 1);
  __syncthreads();
  if (t < N_CLS && h[t]) atomicAdd(&hist[t], h[t]);
}

__global__ void k_scan(const int* __restrict__ hist, int* __restrict__ start) {
  if (threadIdx.x == 0) {
    int run = 0;
    for (int c = 0; c < N_CLS; c++) { start[c] = run; run += hist[c]; }
  }
}

__global__ void k_perm(const int* __restrict__ labels, const int* __restrict__ start,
                       int* __restrict__ cursor, int* __restrict__ perm,
                       int* __restrict__ cls) {
  int n = blockIdx.x * 256 + threadIdx.x;
  if (n < N_KEYS) {
    int l = labels[n];
    int pos = start[l] + atomicAdd(&cursor[l], 1);
    perm[pos] = n;
    cls[pos] = l;
  } else if (n < N_PAD) {
    cls[n] = N_CLS;  // sentinel for pad columns
  }
}

// ------- row L2-normalize, f32 in -> bf16 out (wave per row) -------
__global__ void k_norm(const float* __restrict__ in,
                       unsigned short* __restrict__ out, int rows) {
  int w = threadIdx.x >> 6, lane = threadIdx.x & 63;
  int row = blockIdx.x * 4 + w;
  if (row >= rows) return;
  const float4* src = (const float4*)(in + (size_t)row * D_K) + lane * 2;
  float4 a = src[0], b = src[1];
  float f[8] = {a.x, a.y, a.z, a.w, b.x, b.y, b.z, b.w};
  float ss = 0.f;
#pragma unroll
  for (int i = 0; i < 8; i++) ss += f[i] * f[i];
#pragma unroll
  for (int d = 1; d < 64; d <<= 1) ss += __shfl_xor(ss, d);
  float rinv = rsqrtf(ss);
  *((uint4*)(out + (size_t)row * D_K) + lane) = pack8(f, rinv);
}

// -- gather sorted key row (f32), normalize, write padded bf16 matrix --
__global__ void k_prep(const float* __restrict__ keys,
                       const int* __restrict__ perm, unsigned short* __restrict__ kn) {
  int w = threadIdx.x >> 6, lane = threadIdx.x & 63;
  int j = blockIdx.x * 4 + w;
  if (j >= N_PAD) return;
  uint4* dst = (uint4*)(kn + (size_t)j * D_K) + lane;
  if (j >= N_KEYS) { *dst = make_uint4(0, 0, 0, 0); return; }
  int n = perm[j];
  const float4* src = (const float4*)(keys + (size_t)n * D_K) + lane * 2;
  float4 a = src[0], b = src[1];
  float f[8] = {a.x, a.y, a.z, a.w, b.x, b.y, b.z, b.w};
  float ss = 0.f;
#pragma unroll
  for (int i = 0; i < 8; i++) ss += f[i] * f[i];
#pragma unroll
  for (int d = 1; d < 64; d <<= 1) ss += __shfl_xor(ss, d);
  float rinv = rsqrtf(ss);
  *dst = pack8(f, rinv);
}

// -------- CLIP branch: out[b][c] = 0.5 * 100 * dot(qn_b, tn_c)  (f32 out) -----
// Fully overwrites d_out (poisoned 0xAA) before k_main accumulates into it.
__global__ void k_z(const unsigned short* __restrict__ qn,
                    const unsigned short* __restrict__ tn, float* __restrict__ out) {
  __shared__ float qrow[D_K];
  int t = threadIdx.x, b = blockIdx.x;
  qrow[t]       = bf2f(qn[b * D_K + t]);
  qrow[t + 256] = bf2f(qn[b * D_K + 256 + t]);
  __syncthreads();
  if (t < N_CLS) {
    const uint4* trow = (const uint4*)(tn + (size_t)t * D_K);
    float s = 0.f;
    for (int k8 = 0; k8 < D_K / 8; k8++) {
      uint4 v = trow[k8];
      unsigned short h[8] = {
        (unsigned short)(v.x & 0xffffu), (unsigned short)(v.x >> 16),
        (unsigned short)(v.y & 0xffffu), (unsigned short)(v.y >> 16),
        (unsigned short)(v.z & 0xffffu), (unsigned short)(v.z >> 16),
        (unsigned short)(v.w & 0xffffu), (unsigned short)(v.w >> 16)};
      const float* qp = &qrow[k8 * 8];
#pragma unroll
      for (int i = 0; i < 8; i++) s += bf2f(h[i]) * qp[i];
    }
    out[b * N_CLS + t] = 50.0f * s;  // (1-alpha) * logit_scale = 0.5 * 100
  }
}

// ------- main MFMA GEMM + exp + sorted-class segment reduce + atomic add ------
__global__ __launch_bounds__(256) void k_main(const unsigned short* __restrict__ qn,
                                              const unsigned short* __restrict__ kn,
                                              const int* __restrict__ cls,
                                              float* __restrict__ out) {
  __shared__ unsigned short As[128 * 64];
  __shared__ unsigned short Bs[128 * 64];
  int t = threadIdx.x;
  int tileN = blockIdx.x, tileB = blockIdx.y;
  int rowB0 = tileB * 128, rowN0 = tileN * 128;

  f32x4 acc[4][4];
#pragma unroll
  for (int i = 0; i < 4; i++)
#pragma unroll
    for (int j = 0; j < 4; j++) acc[i][j] = (f32x4){0.f, 0.f, 0.f, 0.f};

  int lane = t & 63, w = t >> 6;
  int wr = (w >> 1) * 64, wc = (w & 1) * 64;
  int l15 = lane & 15, lq = lane >> 4;
  const int rA = t >> 3;        // 0..31: row within a 32-row staging chunk
  const int c8 = (t & 7) * 8;   // bf16 col offset within BK=64

  for (int k0 = 0; k0 < D_K; k0 += 64) {
    uint4 va[4], vb[4];
#pragma unroll
    for (int i = 0; i < 4; i++) {
      int row = i * 32 + rA;
      va[i] = *(const uint4*)(qn + (size_t)(rowB0 + row) * D_K + k0 + c8);
      vb[i] = *(const uint4*)(kn + (size_t)(rowN0 + row) * D_K + k0 + c8);
    }
    __syncthreads();   // all waves done reading previous tile
#pragma unroll
    for (int i = 0; i < 4; i++) {
      *(uint4*)&As[i * 2048 + t * 8] = va[i];
      *(uint4*)&Bs[i * 2048 + t * 8] = vb[i];
    }
    __syncthreads();   // ds_write visible to all waves
#pragma unroll
    for (int ks = 0; ks < 64; ks += 32) {
      bf16x8 af[4], bf[4];
#pragma unroll
      for (int i = 0; i < 4; i++)
        af[i] = *(const bf16x8*)&As[(wr + 16 * i + l15) * 64 + ks + lq * 8];
#pragma unroll
      for (int j = 0; j < 4; j++)
        bf[j] = *(const bf16x8*)&Bs[(wc + 16 * j + l15) * 64 + ks + lq * 8];
#pragma unroll
      for (int i = 0; i < 4; i++)
#pragma unroll
        for (int j = 0; j < 4; j++)
          acc[i][j] = __builtin_amdgcn_mfma_f32_16x16x32_bf16(af[i], bf[j], acc[i][j], 0, 0, 0);
    }
  }

  // epilogue: aff = exp(5*sim); segment-sum over sorted classes; atomicAdd 0.5*sum
#pragma unroll
  for (int i = 0; i < 4; i++)
#pragma unroll
    for (int j = 0; j < 4; j++)
#pragma unroll
      for (int r = 0; r < 4; r++) acc[i][j][r] = __expf(5.0f * acc[i][j][r]);

  int cj[4];
#pragma unroll
  for (int j = 0; j < 4; j++) cj[j] = cls[rowN0 + wc + 16 * j + l15];
  int cseg0 = cls[rowN0 + wc];        // wave-uniform (sorted, nondecreasing)
  int cseg1 = cls[rowN0 + wc + 63];

  for (int c = cseg0; c <= cseg1; c++) {
    if (c >= N_CLS) break;  // pad sentinel; all later cols are pad too
#pragma unroll
    for (int i = 0; i < 4; i++) {
      float s0 = 0.f, s1 = 0.f, s2 = 0.f, s3 = 0.f;
#pragma unroll
      for (int j = 0; j < 4; j++) {
        if (cj[j] == c) {
          s0 += acc[i][j][0]; s1 += acc[i][j][1];
          s2 += acc[i][j][2]; s3 += acc[i][j][3];
        }
      }
#pragma unroll
      for (int d = 1; d < 16; d <<= 1) {
        s0 += __shfl_xor(s0, d); s1 += __shfl_xor(s1, d);
        s2 += __shfl_xor(s2, d); s3 += __shfl_xor(s3, d);
      }
      if (l15 == 0) {
        int row = rowB0 + wr + 16 * i + lq * 4;
        float* o = out + (size_t)row * N_CLS + c;
        if (s0 != 0.f) atomicAdd(o + 0 * N_CLS, 0.5f * s0);
        if (s1 != 0.f) atomicAdd(o + 1 * N_CLS, 0.5f * s1);
        if (s2 != 0.f) atomicAdd(o + 2 * N_CLS, 0.5f * s2);
        if (s3 != 0.f) atomicAdd(o + 3 * N_CLS, 0.5f * s3);
      }
    }
  }
}

extern "C" void kernel_launch(void* const* d_in, const int* in_sizes, int n_in,
                              void* d_out, int out_size, void* d_ws, size_t ws_size,
                              hipStream_t stream) {
  (void)in_sizes; (void)n_in; (void)out_size; (void)ws_size;
  const float* img    = (const float*)d_in[0];
  const float* txt    = (const float*)d_in[1];
  const float* keys   = (const float*)d_in[2];
  const int*   labels = (const int*)d_in[3];
  float*       out    = (float*)d_out;

  char* ws = (char*)d_ws;
  // workspace layout (bytes)
  unsigned short* qn = (unsigned short*)(ws + 0);         // 1024*512*2   = 1,048,576
  unsigned short* tn = (unsigned short*)(ws + 1048576);   //  200*512*2   =   204,800
  unsigned short* kn = (unsigned short*)(ws + 1253376);   // 50048*512*2  = 51,249,152
  int*  perm   = (int*)(ws + 52502528);                   // 50048*4
  int*  cls    = (int*)(ws + 52702720);                   // 50048*4
  int*  hist   = (int*)(ws + 52902912);                   // 256 ints
  int*  cursor = hist + 256;                              // 256 ints
  int*  start  = hist + 512;                              // 256 ints

  hipMemsetAsync(hist, 0, 512 * sizeof(int), stream);  // hist + cursor

  k_hist<<<196, 256, 0, stream>>>(labels, hist);
  k_scan<<<1, 64, 0, stream>>>(hist, start);
  k_perm<<<196, 256, 0, stream>>>(labels, start, cursor, perm, cls);
  k_norm<<<256, 256, 0, stream>>>(img, qn, B_Q);
  k_norm<<<50, 256, 0, stream>>>(txt, tn, N_CLS);
  k_prep<<<N_PAD / 4, 256, 0, stream>>>(keys, perm, kn);
  k_z<<<B_Q, 256, 0, stream>>>(qn, tn, out);
  k_main<<<dim3(N_PAD / 128, B_Q / 128), 256, 0, stream>>>(qn, kn, cls, out);
}

// Round 4
// 339.025 us; speedup vs baseline: 1.4776x; 1.4776x over previous
//
#include <hip/hip_runtime.h>

#define B_Q    1024
#define D_K    512
#define N_CLS  200
#define N_KEYS 50000
#define N_PAD  50048   // 391 * 128

typedef __attribute__((ext_vector_type(8))) short bf16x8;
typedef __attribute__((ext_vector_type(4))) float f32x4;

__device__ __forceinline__ float bf2f(unsigned short u) {
  union { unsigned int i; float f; } v; v.i = ((unsigned int)u) << 16; return v.f;
}
__device__ __forceinline__ unsigned short f2bf(float f) {
  union { float f; unsigned int i; } v; v.f = f;
  unsigned int r = v.i + 0x7fffu + ((v.i >> 16) & 1u);
  return (unsigned short)(r >> 16);
}
__device__ __forceinline__ uint4 pack8(const float f[8], float s) {
  uint4 o;
  o.x = (unsigned)f2bf(f[0]*s) | ((unsigned)f2bf(f[1]*s) << 16);
  o.y = (unsigned)f2bf(f[2]*s) | ((unsigned)f2bf(f[3]*s) << 16);
  o.z = (unsigned)f2bf(f[4]*s) | ((unsigned)f2bf(f[5]*s) << 16);
  o.w = (unsigned)f2bf(f[6]*s) | ((unsigned)f2bf(f[7]*s) << 16);
  return o;
}
__device__ __forceinline__ void async_copy16(const void* g, void* lds) {
  __builtin_amdgcn_global_load_lds(
      (const __attribute__((address_space(1))) unsigned int*)g,
      (__attribute__((address_space(3))) unsigned int*)lds, 16, 0, 0);
}

// ---------------- label sort (counting sort) ----------------
__global__ void k_hist(const int* __restrict__ labels, int* __restrict__ hist) {
  __shared__ int h[N_CLS];
  int t = threadIdx.x;
  if (t < N_CLS) h[t] = 0;
  __syncthreads();
  int n = blockIdx.x * 256 + t;
  if (n < N_KEYS) atomicAdd(&h[labels[n]], 1);
  __syncthreads();
  if (t < N_CLS && h[t]) atomicAdd(&hist[t], h[t]);
}

__global__ void k_scan(const int* __restrict__ hist, int* __restrict__ start) {
  if (threadIdx.x == 0) {
    int run = 0;
    for (int c = 0; c < N_CLS; c++) { start[c] = run; run += hist[c]; }
  }
}

__global__ void k_perm(const int* __restrict__ labels, const int* __restrict__ start,
                       int* __restrict__ cursor, int* __restrict__ perm,
                       int* __restrict__ cls) {
  int n = blockIdx.x * 256 + threadIdx.x;
  if (n < N_KEYS) {
    int l = labels[n];
    int pos = start[l] + atomicAdd(&cursor[l], 1);
    perm[pos] = n;
    cls[pos] = l;
  } else if (n < N_PAD) {
    cls[n] = N_CLS;  // sentinel for pad columns
  }
}

// ------- row L2-normalize, f32 in -> bf16 out (wave per row) -------
__global__ void k_norm(const float* __restrict__ in,
                       unsigned short* __restrict__ out, int rows) {
  int w = threadIdx.x >> 6, lane = threadIdx.x & 63;
  int row = blockIdx.x * 4 + w;
  if (row >= rows) return;
  const float4* src = (const float4*)(in + (size_t)row * D_K) + lane * 2;
  float4 a = src[0], b = src[1];
  float f[8] = {a.x, a.y, a.z, a.w, b.x, b.y, b.z, b.w};
  float ss = 0.f;
#pragma unroll
  for (int i = 0; i < 8; i++) ss += f[i] * f[i];
#pragma unroll
  for (int d = 1; d < 64; d <<= 1) ss += __shfl_xor(ss, d);
  float rinv = rsqrtf(ss);
  *((uint4*)(out + (size_t)row * D_K) + lane) = pack8(f, rinv);
}

// -- gather sorted key row (f32), normalize, write padded bf16 matrix --
__global__ void k_prep(const float* __restrict__ keys,
                       const int* __restrict__ perm, unsigned short* __restrict__ kn) {
  int w = threadIdx.x >> 6, lane = threadIdx.x & 63;
  int j = blockIdx.x * 4 + w;
  if (j >= N_PAD) return;
  uint4* dst = (uint4*)(kn + (size_t)j * D_K) + lane;
  if (j >= N_KEYS) { *dst = make_uint4(0, 0, 0, 0); return; }
  int n = perm[j];
  const float4* src = (const float4*)(keys + (size_t)n * D_K) + lane * 2;
  float4 a = src[0], b = src[1];
  float f[8] = {a.x, a.y, a.z, a.w, b.x, b.y, b.z, b.w};
  float ss = 0.f;
#pragma unroll
  for (int i = 0; i < 8; i++) ss += f[i] * f[i];
#pragma unroll
  for (int d = 1; d < 64; d <<= 1) ss += __shfl_xor(ss, d);
  float rinv = rsqrtf(ss);
  *dst = pack8(f, rinv);
}

// -------- CLIP branch: out[b][c] = 0.5 * 100 * dot(qn_b, tn_c)  (f32 out) -----
// Fully overwrites d_out (poisoned 0xAA) before k_main accumulates into it.
__global__ void k_z(const unsigned short* __restrict__ qn,
                    const unsigned short* __restrict__ tn, float* __restrict__ out) {
  __shared__ float qrow[D_K];
  int t = threadIdx.x, b = blockIdx.x;
  qrow[t]       = bf2f(qn[b * D_K + t]);
  qrow[t + 256] = bf2f(qn[b * D_K + 256 + t]);
  __syncthreads();
  if (t < N_CLS) {
    const uint4* trow = (const uint4*)(tn + (size_t)t * D_K);
    float s = 0.f;
    for (int k8 = 0; k8 < D_K / 8; k8++) {
      uint4 v = trow[k8];
      unsigned short h[8] = {
        (unsigned short)(v.x & 0xffffu), (unsigned short)(v.x >> 16),
        (unsigned short)(v.y & 0xffffu), (unsigned short)(v.y >> 16),
        (unsigned short)(v.z & 0xffffu), (unsigned short)(v.z >> 16),
        (unsigned short)(v.w & 0xffffu), (unsigned short)(v.w >> 16)};
      const float* qp = &qrow[k8 * 8];
#pragma unroll
      for (int i = 0; i < 8; i++) s += bf2f(h[i]) * qp[i];
    }
    out[b * N_CLS + t] = 50.0f * s;  // (1-alpha) * logit_scale = 0.5 * 100
  }
}

// ------- main MFMA GEMM + exp + sorted-class segment reduce + atomic add ------
// m97-style staging: global_load_lds width=16 (no VGPR round-trip). Round-1
// proved the staging style was NOT the NaN cause (dtype was), so async is safe.
// __launch_bounds__(256,3): stop the occupancy heuristic from capping VGPRs at
// ~88 and spilling staging regs to scratch (round-3: 579 MB phantom WRITE_SIZE).
__global__ __launch_bounds__(256, 3) void k_main(const unsigned short* __restrict__ qn,
                                                 const unsigned short* __restrict__ kn,
                                                 const int* __restrict__ cls,
                                                 float* __restrict__ out) {
  __shared__ unsigned short As[128 * 64];
  __shared__ unsigned short Bs[128 * 64];
  int t = threadIdx.x;
  int tileN = blockIdx.x, tileB = blockIdx.y;
  int rowB0 = tileB * 128, rowN0 = tileN * 128;

  f32x4 acc[4][4];
#pragma unroll
  for (int i = 0; i < 4; i++)
#pragma unroll
    for (int j = 0; j < 4; j++) acc[i][j] = (f32x4){0.f, 0.f, 0.f, 0.f};

  int lane = t & 63, w = t >> 6;
  int wr = (w >> 1) * 64, wc = (w & 1) * 64;
  int l15 = lane & 15, lq = lane >> 4;
  const int rA = t >> 3;        // 0..31: row within a 32-row staging chunk
  const int c8 = (t & 7) * 8;   // bf16 col offset within BK=64

  for (int k0 = 0; k0 < D_K; k0 += 64) {
    __syncthreads();   // all waves done reading previous tile
#pragma unroll
    for (int i = 0; i < 4; i++) {
      int row = i * 32 + rA;
      async_copy16(qn + (size_t)(rowB0 + row) * D_K + k0 + c8, &As[i * 2048 + t * 8]);
      async_copy16(kn + (size_t)(rowN0 + row) * D_K + k0 + c8, &Bs[i * 2048 + t * 8]);
    }
    __syncthreads();   // vmcnt(0) drained before s_barrier -> LDS valid
#pragma unroll
    for (int ks = 0; ks < 64; ks += 32) {
      bf16x8 af[4], bf[4];
#pragma unroll
      for (int i = 0; i < 4; i++)
        af[i] = *(const bf16x8*)&As[(wr + 16 * i + l15) * 64 + ks + lq * 8];
#pragma unroll
      for (int j = 0; j < 4; j++)
        bf[j] = *(const bf16x8*)&Bs[(wc + 16 * j + l15) * 64 + ks + lq * 8];
#pragma unroll
      for (int i = 0; i < 4; i++)
#pragma unroll
        for (int j = 0; j < 4; j++)
          acc[i][j] = __builtin_amdgcn_mfma_f32_16x16x32_bf16(af[i], bf[j], acc[i][j], 0, 0, 0);
    }
  }

  // epilogue: aff = exp(5*sim); segment-sum over sorted classes; atomicAdd 0.5*sum
#pragma unroll
  for (int i = 0; i < 4; i++)
#pragma unroll
    for (int j = 0; j < 4; j++)
#pragma unroll
      for (int r = 0; r < 4; r++) acc[i][j][r] = __expf(5.0f * acc[i][j][r]);

  int cj[4];
#pragma unroll
  for (int j = 0; j < 4; j++) cj[j] = cls[rowN0 + wc + 16 * j + l15];
  int cseg0 = cls[rowN0 + wc];        // wave-uniform (sorted, nondecreasing)
  int cseg1 = cls[rowN0 + wc + 63];

  for (int c = cseg0; c <= cseg1; c++) {
    if (c >= N_CLS) break;  // pad sentinel; all later cols are pad too
#pragma unroll
    for (int i = 0; i < 4; i++) {
      float s0 = 0.f, s1 = 0.f, s2 = 0.f, s3 = 0.f;
#pragma unroll
      for (int j = 0; j < 4; j++) {
        if (cj[j] == c) {
          s0 += acc[i][j][0]; s1 += acc[i][j][1];
          s2 += acc[i][j][2]; s3 += acc[i][j][3];
        }
      }
#pragma unroll
      for (int d = 1; d < 16; d <<= 1) {
        s0 += __shfl_xor(s0, d); s1 += __shfl_xor(s1, d);
        s2 += __shfl_xor(s2, d); s3 += __shfl_xor(s3, d);
      }
      if (l15 == 0) {
        int row = rowB0 + wr + 16 * i + lq * 4;
        float* o = out + (size_t)row * N_CLS + c;
        if (s0 != 0.f) atomicAdd(o + 0 * N_CLS, 0.5f * s0);
        if (s1 != 0.f) atomicAdd(o + 1 * N_CLS, 0.5f * s1);
        if (s2 != 0.f) atomicAdd(o + 2 * N_CLS, 0.5f * s2);
        if (s3 != 0.f) atomicAdd(o + 3 * N_CLS, 0.5f * s3);
      }
    }
  }
}

extern "C" void kernel_launch(void* const* d_in, const int* in_sizes, int n_in,
                              void* d_out, int out_size, void* d_ws, size_t ws_size,
                              hipStream_t stream) {
  (void)in_sizes; (void)n_in; (void)out_size; (void)ws_size;
  const float* img    = (const float*)d_in[0];
  const float* txt    = (const float*)d_in[1];
  const float* keys   = (const float*)d_in[2];
  const int*   labels = (const int*)d_in[3];
  float*       out    = (float*)d_out;

  char* ws = (char*)d_ws;
  // workspace layout (bytes)
  unsigned short* qn = (unsigned short*)(ws + 0);         // 1024*512*2   = 1,048,576
  unsigned short* tn = (unsigned short*)(ws + 1048576);   //  200*512*2   =   204,800
  unsigned short* kn = (unsigned short*)(ws + 1253376);   // 50048*512*2  = 51,249,152
  int*  perm   = (int*)(ws + 52502528);                   // 50048*4
  int*  cls    = (int*)(ws + 52702720);                   // 50048*4
  int*  hist   = (int*)(ws + 52902912);                   // 256 ints
  int*  cursor = hist + 256;                              // 256 ints
  int*  start  = hist + 512;                              // 256 ints

  hipMemsetAsync(hist, 0, 512 * sizeof(int), stream);  // hist + cursor

  k_hist<<<196, 256, 0, stream>>>(labels, hist);
  k_scan<<<1, 64, 0, stream>>>(hist, start);
  k_perm<<<196, 256, 0, stream>>>(labels, start, cursor, perm, cls);
  k_norm<<<256, 256, 0, stream>>>(img, qn, B_Q);
  k_norm<<<50, 256, 0, stream>>>(txt, tn, N_CLS);
  k_prep<<<N_PAD / 4, 256, 0, stream>>>(keys, perm, kn);
  k_z<<<B_Q, 256, 0, stream>>>(qn, tn, out);
  k_main<<<dim3(N_PAD / 128, B_Q / 128), 256, 0, stream>>>(qn, kn, cls, out);
}

// Round 5
// 309.256 us; speedup vs baseline: 1.6198x; 1.0963x over previous
//
#include <hip/hip_runtime.h>

#define B_Q    1024
#define D_K    512
#define N_CLS  200
#define N_KEYS 50000
#define N_PAD  50048   // 391 * 128

typedef __attribute__((ext_vector_type(8))) short bf16x8;
typedef __attribute__((ext_vector_type(4))) float f32x4;

__device__ __forceinline__ float bf2f(unsigned short u) {
  union { unsigned int i; float f; } v; v.i = ((unsigned int)u) << 16; return v.f;
}
__device__ __forceinline__ unsigned short f2bf(float f) {
  union { float f; unsigned int i; } v; v.f = f;
  unsigned int r = v.i + 0x7fffu + ((v.i >> 16) & 1u);
  return (unsigned short)(r >> 16);
}
__device__ __forceinline__ uint4 pack8(const float f[8], float s) {
  uint4 o;
  o.x = (unsigned)f2bf(f[0]*s) | ((unsigned)f2bf(f[1]*s) << 16);
  o.y = (unsigned)f2bf(f[2]*s) | ((unsigned)f2bf(f[3]*s) << 16);
  o.z = (unsigned)f2bf(f[4]*s) | ((unsigned)f2bf(f[5]*s) << 16);
  o.w = (unsigned)f2bf(f[6]*s) | ((unsigned)f2bf(f[7]*s) << 16);
  return o;
}
__device__ __forceinline__ void async_copy16(const void* g, void* lds) {
  __builtin_amdgcn_global_load_lds(
      (const __attribute__((address_space(1))) unsigned int*)g,
      (__attribute__((address_space(3))) unsigned int*)lds, 16, 0, 0);
}

// ---------------- label sort (two-level counting sort) ----------------
__global__ void k_hist(const int* __restrict__ labels, int* __restrict__ hist) {
  __shared__ int h[N_CLS];
  int t = threadIdx.x;
  if (t < N_CLS) h[t] = 0;
  __syncthreads();
  int n = blockIdx.x * 256 + t;
  if (n < N_KEYS) atomicAdd(&h[labels[n]], 1);
  __syncthreads();
  if (t < N_CLS && h[t]) atomicAdd(&hist[t], h[t]);
}

// Parallel exclusive scan (one block). cursor[c] = segment start of class c.
__global__ void k_scan(const int* __restrict__ hist, int* __restrict__ cursor) {
  __shared__ int s[N_CLS];
  int t = threadIdx.x;
  int v = (t < N_CLS) ? hist[t] : 0;
  if (t < N_CLS) s[t] = v;
  __syncthreads();
  for (int d = 1; d < N_CLS; d <<= 1) {
    int x = 0;
    if (t < N_CLS && t >= d) x = s[t - d];
    __syncthreads();
    if (t < N_CLS) s[t] += x;
    __syncthreads();
  }
  if (t < N_CLS) cursor[t] = s[t] - v;  // exclusive prefix
}

// Block-aggregated scatter: LDS histogram + ONE global atomic per class per
// block (196-deep contention instead of 250-deep per-element), LDS-local rank.
__global__ void k_perm(const int* __restrict__ labels, int* __restrict__ cursor,
                       int* __restrict__ perm, int* __restrict__ cls) {
  __shared__ int lh[N_CLS];
  __shared__ int lbase[N_CLS];
  int t = threadIdx.x;
  if (t < N_CLS) lh[t] = 0;
  __syncthreads();
  int n = blockIdx.x * 256 + t;
  bool valid = (n < N_KEYS);
  int l = 0, lo = 0;
  if (valid) { l = labels[n]; lo = atomicAdd(&lh[l], 1); }
  __syncthreads();
  if (t < N_CLS && lh[t] > 0) lbase[t] = atomicAdd(&cursor[t], lh[t]);
  __syncthreads();
  if (valid) {
    int pos = lbase[l] + lo;
    perm[pos] = n;
    cls[pos] = l;
  } else if (n < N_PAD) {
    cls[n] = N_CLS;  // sentinel for pad columns
  }
}

// ------- row L2-normalize, f32 in -> bf16 out (wave per row; img+txt fused) ---
__global__ void k_norm2(const float* __restrict__ img, const float* __restrict__ txt,
                        unsigned short* __restrict__ qn, unsigned short* __restrict__ tn) {
  int w = threadIdx.x >> 6, lane = threadIdx.x & 63;
  int row = blockIdx.x * 4 + w;
  const float* in; unsigned short* out; int r;
  if (row < B_Q)                { in = img; out = qn; r = row; }
  else if (row < B_Q + N_CLS)   { in = txt; out = tn; r = row - B_Q; }
  else return;
  const float4* src = (const float4*)(in + (size_t)r * D_K) + lane * 2;
  float4 a = src[0], b = src[1];
  float f[8] = {a.x, a.y, a.z, a.w, b.x, b.y, b.z, b.w};
  float ss = 0.f;
#pragma unroll
  for (int i = 0; i < 8; i++) ss += f[i] * f[i];
#pragma unroll
  for (int d = 1; d < 64; d <<= 1) ss += __shfl_xor(ss, d);
  float rinv = rsqrtf(ss);
  *((uint4*)(out + (size_t)r * D_K) + lane) = pack8(f, rinv);
}

// -- gather sorted key row (f32), normalize, write padded bf16 matrix --
__global__ void k_prep(const float* __restrict__ keys,
                       const int* __restrict__ perm, unsigned short* __restrict__ kn) {
  int w = threadIdx.x >> 6, lane = threadIdx.x & 63;
  int j = blockIdx.x * 4 + w;
  if (j >= N_PAD) return;
  uint4* dst = (uint4*)(kn + (size_t)j * D_K) + lane;
  if (j >= N_KEYS) { *dst = make_uint4(0, 0, 0, 0); return; }
  int n = perm[j];
  const float4* src = (const float4*)(keys + (size_t)n * D_K) + lane * 2;
  float4 a = src[0], b = src[1];
  float f[8] = {a.x, a.y, a.z, a.w, b.x, b.y, b.z, b.w};
  float ss = 0.f;
#pragma unroll
  for (int i = 0; i < 8; i++) ss += f[i] * f[i];
#pragma unroll
  for (int d = 1; d < 64; d <<= 1) ss += __shfl_xor(ss, d);
  float rinv = rsqrtf(ss);
  *dst = pack8(f, rinv);
}

// -------- CLIP branch: out[b][c] = 0.5 * 100 * dot(qn_b, tn_c)  (f32 out) -----
__global__ void k_z(const unsigned short* __restrict__ qn,
                    const unsigned short* __restrict__ tn, float* __restrict__ out) {
  __shared__ float qrow[D_K];
  int t = threadIdx.x, b = blockIdx.x;
  qrow[t]       = bf2f(qn[b * D_K + t]);
  qrow[t + 256] = bf2f(qn[b * D_K + 256 + t]);
  __syncthreads();
  if (t < N_CLS) {
    const uint4* trow = (const uint4*)(tn + (size_t)t * D_K);
    float s = 0.f;
    for (int k8 = 0; k8 < D_K / 8; k8++) {
      uint4 v = trow[k8];
      unsigned short h[8] = {
        (unsigned short)(v.x & 0xffffu), (unsigned short)(v.x >> 16),
        (unsigned short)(v.y & 0xffffu), (unsigned short)(v.y >> 16),
        (unsigned short)(v.z & 0xffffu), (unsigned short)(v.z >> 16),
        (unsigned short)(v.w & 0xffffu), (unsigned short)(v.w >> 16)};
      const float* qp = &qrow[k8 * 8];
#pragma unroll
      for (int i = 0; i < 8; i++) s += bf2f(h[i]) * qp[i];
    }
    out[b * N_CLS + t] = 50.0f * s;  // (1-alpha) * logit_scale = 0.5 * 100
  }
}

// ------- main MFMA GEMM + exp + sorted-class segment reduce + atomic add ------
// XOR column-group swizzle on the STAGING SOURCE (LDS dest of global_load_lds is
// lane-fixed, so we permute which global 16B each lane fetches); fragment reads
// un-swizzle with group ^ (row&7). Kills the 16-way quad-bank conflicts
// (round-4: SQ_LDS_BANK_CONFLICT=1.9e7 ~= +12 cyc/ds_read_b128).
// Grid: tileB fast (x), tileN slow (y) so the 8 blocks sharing a kn slab are
// dispatch-adjacent -> kn fetched ~once from HBM (round-4: 206 MB = 4x kn).
__global__ __launch_bounds__(256, 3) void k_main(const unsigned short* __restrict__ qn,
                                                 const unsigned short* __restrict__ kn,
                                                 const int* __restrict__ cls,
                                                 float* __restrict__ out) {
  __shared__ unsigned short As[128 * 64];
  __shared__ unsigned short Bs[128 * 64];
  int t = threadIdx.x;
  int tileB = blockIdx.x, tileN = blockIdx.y;
  int rowB0 = tileB * 128, rowN0 = tileN * 128;

  f32x4 acc[4][4];
#pragma unroll
  for (int i = 0; i < 4; i++)
#pragma unroll
    for (int j = 0; j < 4; j++) acc[i][j] = (f32x4){0.f, 0.f, 0.f, 0.f};

  int lane = t & 63, w = t >> 6;
  int wr = (w >> 1) * 64, wc = (w & 1) * 64;
  int l15 = lane & 15, lq = lane >> 4;
  const int rA = t >> 3;                       // 0..31: row within 32-row chunk
  const int gsw = ((t & 7) ^ (rA & 7)) * 8;    // swizzled source col (shorts)
  const int sw = l15 & 7;                      // un-swizzle key for frag reads

  for (int k0 = 0; k0 < D_K; k0 += 64) {
    __syncthreads();
#pragma unroll
    for (int i = 0; i < 4; i++) {
      int row = i * 32 + rA;
      async_copy16(qn + (size_t)(rowB0 + row) * D_K + k0 + gsw, &As[i * 2048 + t * 8]);
      async_copy16(kn + (size_t)(rowN0 + row) * D_K + k0 + gsw, &Bs[i * 2048 + t * 8]);
    }
    __syncthreads();
#pragma unroll
    for (int ks = 0; ks < 64; ks += 32) {
      bf16x8 af[4], bf[4];
#pragma unroll
      for (int i = 0; i < 4; i++)
        af[i] = *(const bf16x8*)&As[(wr + 16 * i + l15) * 64 + ((((ks >> 3) + lq) ^ sw) * 8)];
#pragma unroll
      for (int j = 0; j < 4; j++)
        bf[j] = *(const bf16x8*)&Bs[(wc + 16 * j + l15) * 64 + ((((ks >> 3) + lq) ^ sw) * 8)];
#pragma unroll
      for (int i = 0; i < 4; i++)
#pragma unroll
        for (int j = 0; j < 4; j++)
          acc[i][j] = __builtin_amdgcn_mfma_f32_16x16x32_bf16(af[i], bf[j], acc[i][j], 0, 0, 0);
    }
  }

  // epilogue: aff = exp(5*sim); segment-sum over sorted classes; atomicAdd 0.5*sum
#pragma unroll
  for (int i = 0; i < 4; i++)
#pragma unroll
    for (int j = 0; j < 4; j++)
#pragma unroll
      for (int r = 0; r < 4; r++) acc[i][j][r] = __expf(5.0f * acc[i][j][r]);

  int cj[4];
#pragma unroll
  for (int j = 0; j < 4; j++) cj[j] = cls[rowN0 + wc + 16 * j + l15];
  int cseg0 = cls[rowN0 + wc];        // wave-uniform (sorted, nondecreasing)
  int cseg1 = cls[rowN0 + wc + 63];

  for (int c = cseg0; c <= cseg1; c++) {
    if (c >= N_CLS) break;  // pad sentinel; all later cols are pad too
#pragma unroll
    for (int i = 0; i < 4; i++) {
      float s0 = 0.f, s1 = 0.f, s2 = 0.f, s3 = 0.f;
#pragma unroll
      for (int j = 0; j < 4; j++) {
        if (cj[j] == c) {
          s0 += acc[i][j][0]; s1 += acc[i][j][1];
          s2 += acc[i][j][2]; s3 += acc[i][j][3];
        }
      }
#pragma unroll
      for (int d = 1; d < 16; d <<= 1) {
        s0 += __shfl_xor(s0, d); s1 += __shfl_xor(s1, d);
        s2 += __shfl_xor(s2, d); s3 += __shfl_xor(s3, d);
      }
      if (l15 == 0) {
        int row = rowB0 + wr + 16 * i + lq * 4;
        float* o = out + (size_t)row * N_CLS + c;
        if (s0 != 0.f) atomicAdd(o + 0 * N_CLS, 0.5f * s0);
        if (s1 != 0.f) atomicAdd(o + 1 * N_CLS, 0.5f * s1);
        if (s2 != 0.f) atomicAdd(o + 2 * N_CLS, 0.5f * s2);
        if (s3 != 0.f) atomicAdd(o + 3 * N_CLS, 0.5f * s3);
      }
    }
  }
}

extern "C" void kernel_launch(void* const* d_in, const int* in_sizes, int n_in,
                              void* d_out, int out_size, void* d_ws, size_t ws_size,
                              hipStream_t stream) {
  (void)in_sizes; (void)n_in; (void)out_size; (void)ws_size;
  const float* img    = (const float*)d_in[0];
  const float* txt    = (const float*)d_in[1];
  const float* keys   = (const float*)d_in[2];
  const int*   labels = (const int*)d_in[3];
  float*       out    = (float*)d_out;

  char* ws = (char*)d_ws;
  // workspace layout (bytes)
  unsigned short* qn = (unsigned short*)(ws + 0);         // 1024*512*2   = 1,048,576
  unsigned short* tn = (unsigned short*)(ws + 1048576);   //  200*512*2   =   204,800
  unsigned short* kn = (unsigned short*)(ws + 1253376);   // 50048*512*2  = 51,249,152
  int*  perm   = (int*)(ws + 52502528);                   // 50048*4
  int*  cls    = (int*)(ws + 52702720);                   // 50048*4
  int*  hist   = (int*)(ws + 52902912);                   // 256 ints
  int*  cursor = hist + 256;                              // 256 ints

  hipMemsetAsync(hist, 0, 256 * sizeof(int), stream);

  k_hist<<<196, 256, 0, stream>>>(labels, hist);
  k_scan<<<1, 256, 0, stream>>>(hist, cursor);
  k_perm<<<196, 256, 0, stream>>>(labels, cursor, perm, cls);
  k_norm2<<<(B_Q + N_CLS + 3) / 4, 256, 0, stream>>>(img, txt, qn, tn);
  k_prep<<<N_PAD / 4, 256, 0, stream>>>(keys, perm, kn);
  k_z<<<B_Q, 256, 0, stream>>>(qn, tn, out);
  k_main<<<dim3(B_Q / 128, N_PAD / 128), 256, 0, stream>>>(qn, kn, cls, out);
}

// Round 6
// 297.362 us; speedup vs baseline: 1.6846x; 1.0400x over previous
//
#include <hip/hip_runtime.h>

#define B_Q    1024
#define D_K    512
#define N_CLS  200
#define N_KEYS 50000
#define N_PAD  50048            // 391 * 128 (sorted keys, padded)
#define N_EXT  (N_PAD + 256)    // + 200 text rows + 56 zero rows
#define N_ZT   (N_PAD / 128)    // 391: first z-tile index

typedef __attribute__((ext_vector_type(8))) short bf16x8;
typedef __attribute__((ext_vector_type(4))) float f32x4;

__device__ __forceinline__ unsigned short f2bf(float f) {
  union { float f; unsigned int i; } v; v.f = f;
  unsigned int r = v.i + 0x7fffu + ((v.i >> 16) & 1u);
  return (unsigned short)(r >> 16);
}
__device__ __forceinline__ uint4 pack8(const float f[8], float s) {
  uint4 o;
  o.x = (unsigned)f2bf(f[0]*s) | ((unsigned)f2bf(f[1]*s) << 16);
  o.y = (unsigned)f2bf(f[2]*s) | ((unsigned)f2bf(f[3]*s) << 16);
  o.z = (unsigned)f2bf(f[4]*s) | ((unsigned)f2bf(f[5]*s) << 16);
  o.w = (unsigned)f2bf(f[6]*s) | ((unsigned)f2bf(f[7]*s) << 16);
  return o;
}
__device__ __forceinline__ void async_copy16(const void* g, void* lds) {
  __builtin_amdgcn_global_load_lds(
      (const __attribute__((address_space(1))) unsigned int*)g,
      (__attribute__((address_space(3))) unsigned int*)lds, 16, 0, 0);
}

// ---------------- label sort (two-level counting sort) ----------------
__global__ void k_hist(const int* __restrict__ labels, int* __restrict__ hist) {
  __shared__ int h[N_CLS];
  int t = threadIdx.x;
  if (t < N_CLS) h[t] = 0;
  __syncthreads();
  int n = blockIdx.x * 256 + t;
  if (n < N_KEYS) atomicAdd(&h[labels[n]], 1);
  __syncthreads();
  if (t < N_CLS && h[t]) atomicAdd(&hist[t], h[t]);
}

// Parallel exclusive scan (one block). cursor[c] = segment start of class c.
__global__ void k_scan(const int* __restrict__ hist, int* __restrict__ cursor) {
  __shared__ int s[N_CLS];
  int t = threadIdx.x;
  int v = (t < N_CLS) ? hist[t] : 0;
  if (t < N_CLS) s[t] = v;
  __syncthreads();
  for (int d = 1; d < N_CLS; d <<= 1) {
    int x = 0;
    if (t < N_CLS && t >= d) x = s[t - d];
    __syncthreads();
    if (t < N_CLS) s[t] += x;
    __syncthreads();
  }
  if (t < N_CLS) cursor[t] = s[t] - v;  // exclusive prefix
}

// Block-aggregated rank: dest[n] = sorted position of key n (coalesced write).
__global__ void k_perm(const int* __restrict__ labels, int* __restrict__ cursor,
                       int* __restrict__ dest) {
  __shared__ int lh[N_CLS];
  __shared__ int lbase[N_CLS];
  int t = threadIdx.x;
  if (t < N_CLS) lh[t] = 0;
  __syncthreads();
  int n = blockIdx.x * 256 + t;
  bool valid = (n < N_KEYS);
  int l = 0, lo = 0;
  if (valid) { l = labels[n]; lo = atomicAdd(&lh[l], 1); }
  __syncthreads();
  if (t < N_CLS && lh[t] > 0) lbase[t] = atomicAdd(&cursor[t], lh[t]);
  __syncthreads();
  if (valid) dest[n] = lbase[l] + lo;
}

// ---- fused prep: keys(stream-read, normalize, scatter-write sorted) + img
// ---- normalize -> qn + txt normalize -> kn tail + zero pad rows. Wave/row.
__global__ void k_prep2(const float* __restrict__ keys, const float* __restrict__ img,
                        const float* __restrict__ txt, const int* __restrict__ labels,
                        const int* __restrict__ dest, unsigned short* __restrict__ qn,
                        unsigned short* __restrict__ kn, int* __restrict__ cls) {
  int w = threadIdx.x >> 6, lane = threadIdx.x & 63;
  int row = blockIdx.x * 4 + w;
  const float* src; unsigned short* dst; int r;
  if (row < N_PAD) {
    if (row >= N_KEYS) {  // pad row: zero + sentinel
      *((uint4*)(kn + (size_t)row * D_K) + lane) = make_uint4(0, 0, 0, 0);
      if (lane == 0) cls[row] = N_CLS;
      return;
    }
    int d = dest[row];
    if (lane == 0) cls[d] = labels[row];
    src = keys + (size_t)row * D_K;
    dst = kn + (size_t)d * D_K;
  } else if (row < N_PAD + B_Q) {
    r = row - N_PAD;
    src = img + (size_t)r * D_K;
    dst = qn + (size_t)r * D_K;
  } else if (row < N_PAD + B_Q + N_CLS) {
    r = row - N_PAD - B_Q;
    src = txt + (size_t)r * D_K;
    dst = kn + (size_t)(N_PAD + r) * D_K;
  } else if (row < N_PAD + B_Q + N_CLS + 56) {
    r = N_PAD + N_CLS + (row - N_PAD - B_Q - N_CLS);  // zero tail rows
    *((uint4*)(kn + (size_t)r * D_K) + lane) = make_uint4(0, 0, 0, 0);
    return;
  } else return;
  const float4* s4 = (const float4*)src + lane * 2;
  float4 a = s4[0], b = s4[1];
  float f[8] = {a.x, a.y, a.z, a.w, b.x, b.y, b.z, b.w};
  float ss = 0.f;
#pragma unroll
  for (int i = 0; i < 8; i++) ss += f[i] * f[i];
#pragma unroll
  for (int d = 1; d < 64; d <<= 1) ss += __shfl_xor(ss, d);
  float rinv = rsqrtf(ss);
  *((uint4*)dst + lane) = pack8(f, rinv);
}

// ------- main MFMA GEMM, double-buffered LDS, fused z + c epilogues -------
// Double-buffer: barrier FIRST, then issue next-tile global_load_lds, then
// compute current tile -> copies(k+1) fly during compute(k); the vmcnt(0)
// drain at the next barrier is mostly covered. One barrier per K-iter.
// XOR source-column swizzle (round-5: conflicts 1.9e7 -> 0) retained.
// tileN >= N_ZT are text tiles: epilogue adds 50*sim directly (out pre-zeroed).
__global__ __launch_bounds__(256, 2) void k_main(const unsigned short* __restrict__ qn,
                                                 const unsigned short* __restrict__ kn,
                                                 const int* __restrict__ cls,
                                                 float* __restrict__ out) {
  __shared__ unsigned short As[2][128 * 64];
  __shared__ unsigned short Bs[2][128 * 64];
  int t = threadIdx.x;
  int tileB = blockIdx.x, tileN = blockIdx.y;
  int rowB0 = tileB * 128, rowN0 = tileN * 128;

  f32x4 acc[4][4];
#pragma unroll
  for (int i = 0; i < 4; i++)
#pragma unroll
    for (int j = 0; j < 4; j++) acc[i][j] = (f32x4){0.f, 0.f, 0.f, 0.f};

  int lane = t & 63, w = t >> 6;
  int wr = (w >> 1) * 64, wc = (w & 1) * 64;
  int l15 = lane & 15, lq = lane >> 4;
  const int rA = t >> 3;                       // 0..31: row within 32-row chunk
  const int gsw = ((t & 7) ^ (rA & 7)) * 8;    // swizzled source col (shorts)
  const int sw = l15 & 7;                      // un-swizzle key for frag reads

  // prologue: stage tile 0 into buffer 0
#pragma unroll
  for (int i = 0; i < 4; i++) {
    int row = i * 32 + rA;
    async_copy16(qn + (size_t)(rowB0 + row) * D_K + gsw, &As[0][i * 2048 + t * 8]);
    async_copy16(kn + (size_t)(rowN0 + row) * D_K + gsw, &Bs[0][i * 2048 + t * 8]);
  }

  for (int kt = 0; kt < 8; kt++) {
    int cur = kt & 1;
    __syncthreads();  // drains vmcnt: copies(kt) landed; prev compute finished
    if (kt < 7) {
      int nxt = cur ^ 1, k0 = (kt + 1) * 64;
#pragma unroll
      for (int i = 0; i < 4; i++) {
        int row = i * 32 + rA;
        async_copy16(qn + (size_t)(rowB0 + row) * D_K + k0 + gsw, &As[nxt][i * 2048 + t * 8]);
        async_copy16(kn + (size_t)(rowN0 + row) * D_K + k0 + gsw, &Bs[nxt][i * 2048 + t * 8]);
      }
    }
#pragma unroll
    for (int ks = 0; ks < 64; ks += 32) {
      bf16x8 af[4], bf[4];
#pragma unroll
      for (int i = 0; i < 4; i++)
        af[i] = *(const bf16x8*)&As[cur][(wr + 16 * i + l15) * 64 + ((((ks >> 3) + lq) ^ sw) * 8)];
#pragma unroll
      for (int j = 0; j < 4; j++)
        bf[j] = *(const bf16x8*)&Bs[cur][(wc + 16 * j + l15) * 64 + ((((ks >> 3) + lq) ^ sw) * 8)];
#pragma unroll
      for (int i = 0; i < 4; i++)
#pragma unroll
        for (int j = 0; j < 4; j++)
          acc[i][j] = __builtin_amdgcn_mfma_f32_16x16x32_bf16(af[i], bf[j], acc[i][j], 0, 0, 0);
    }
  }

  if (tileN >= N_ZT) {
    // z-tile: out[row][col] += 0.5 * 100 * sim  (out pre-zeroed; unique writer)
#pragma unroll
    for (int i = 0; i < 4; i++)
#pragma unroll
      for (int j = 0; j < 4; j++) {
        int col = rowN0 + wc + 16 * j + l15 - N_PAD;
        if (col < N_CLS) {
#pragma unroll
          for (int r = 0; r < 4; r++) {
            int row = rowB0 + wr + 16 * i + lq * 4 + r;
            atomicAdd(out + (size_t)row * N_CLS + col, 50.0f * acc[i][j][r]);
          }
        }
      }
    return;
  }

  // c-tile: aff = exp(5*sim); segment-sum over sorted classes; atomicAdd 0.5*sum
#pragma unroll
  for (int i = 0; i < 4; i++)
#pragma unroll
    for (int j = 0; j < 4; j++)
#pragma unroll
      for (int r = 0; r < 4; r++) acc[i][j][r] = __expf(5.0f * acc[i][j][r]);

  int cj[4];
#pragma unroll
  for (int j = 0; j < 4; j++) cj[j] = cls[rowN0 + wc + 16 * j + l15];
  int cseg0 = cls[rowN0 + wc];        // wave-uniform (sorted, nondecreasing)
  int cseg1 = cls[rowN0 + wc + 63];

  for (int c = cseg0; c <= cseg1; c++) {
    if (c >= N_CLS) break;  // pad sentinel; all later cols are pad too
#pragma unroll
    for (int i = 0; i < 4; i++) {
      float s0 = 0.f, s1 = 0.f, s2 = 0.f, s3 = 0.f;
#pragma unroll
      for (int j = 0; j < 4; j++) {
        if (cj[j] == c) {
          s0 += acc[i][j][0]; s1 += acc[i][j][1];
          s2 += acc[i][j][2]; s3 += acc[i][j][3];
        }
      }
#pragma unroll
      for (int d = 1; d < 16; d <<= 1) {
        s0 += __shfl_xor(s0, d); s1 += __shfl_xor(s1, d);
        s2 += __shfl_xor(s2, d); s3 += __shfl_xor(s3, d);
      }
      if (l15 == 0) {
        int row = rowB0 + wr + 16 * i + lq * 4;
        float* o = out + (size_t)row * N_CLS + c;
        if (s0 != 0.f) atomicAdd(o + 0 * N_CLS, 0.5f * s0);
        if (s1 != 0.f) atomicAdd(o + 1 * N_CLS, 0.5f * s1);
        if (s2 != 0.f) atomicAdd(o + 2 * N_CLS, 0.5f * s2);
        if (s3 != 0.f) atomicAdd(o + 3 * N_CLS, 0.5f * s3);
      }
    }
  }
}

extern "C" void kernel_launch(void* const* d_in, const int* in_sizes, int n_in,
                              void* d_out, int out_size, void* d_ws, size_t ws_size,
                              hipStream_t stream) {
  (void)in_sizes; (void)n_in; (void)out_size; (void)ws_size;
  const float* img    = (const float*)d_in[0];
  const float* txt    = (const float*)d_in[1];
  const float* keys   = (const float*)d_in[2];
  const int*   labels = (const int*)d_in[3];
  float*       out    = (float*)d_out;

  char* ws = (char*)d_ws;
  // workspace layout (bytes)
  unsigned short* qn = (unsigned short*)(ws + 0);         // 1024*512*2      = 1,048,576
  unsigned short* kn = (unsigned short*)(ws + 1048576);   // 50304*512*2     = 51,511,296
  int*  dest   = (int*)(ws + 52559872);                   // 50048*4
  int*  cls    = (int*)(ws + 52760064);                   // 50048*4
  int*  hist   = (int*)(ws + 52960256);                   // 256 ints
  int*  cursor = (int*)(ws + 52961280);                   // 256 ints

  hipMemsetAsync(hist, 0, 256 * sizeof(int), stream);
  hipMemsetAsync(out, 0, (size_t)B_Q * N_CLS * sizeof(float), stream);

  k_hist<<<196, 256, 0, stream>>>(labels, hist);
  k_scan<<<1, 256, 0, stream>>>(hist, cursor);
  k_perm<<<196, 256, 0, stream>>>(labels, cursor, dest);
  k_prep2<<<(N_PAD + B_Q + N_CLS + 56 + 3) / 4, 256, 0, stream>>>(
      keys, img, txt, labels, dest, qn, kn, cls);
  k_main<<<dim3(B_Q / 128, N_ZT + 2), 256, 0, stream>>>(qn, kn, cls, out);
}